// Round 12
// baseline (5748.146 us; speedup 1.0000x reference)
//
#include <hip/hip_runtime.h>
#include <hip/hip_fp16.h>

#define Tn 4096
#define Bn 128
#define Hn 128
#define G3 384
#define NTH 256  // 4 waves: 0-1 r/z matvec+gates, 2 n-matvec, 3 heads+coupling

typedef unsigned short u16;
typedef unsigned int u32;
typedef _Float16 f16;
typedef _Float16 h2 __attribute__((ext_vector_type(2)));

__device__ __forceinline__ float sigm(float v) { return 1.f / (1.f + __expf(-v)); }
__device__ __forceinline__ float tanh_fast(float v) {
  v = fminf(fmaxf(v, -15.f), 15.f);
  float e = __expf(-2.f * v);
  return (1.f - e) / (1.f + e);
}
__device__ __forceinline__ u16 f2h(float f) { return __half_as_ushort(__float2half(f)); }
__device__ __forceinline__ float h2f(u16 u) { return __half2float(__ushort_as_half(u)); }
__device__ __forceinline__ h2 bch2(u32 v) { union { u32 u; h2 h; } t; t.u = v; return t.h; }
__device__ __forceinline__ float fdot2f(h2 a, h2 b, float c) {
  return __builtin_amdgcn_fdot2(a, b, c, false);
}

// ============ combo: blocks 0..127 = encoder, 128..255 = decoder ============
// R11 structure + group-ahead VMEM double-buffer: each 8-slot group's global
// batch (gi / x / eps) is issued one group early, so no slot waits on VMEM.
__global__ __launch_bounds__(NTH, 1) void combo_kernel(
    const float* __restrict__ x, const float* __restrict__ Wi_e,
    const float* __restrict__ Wh_e, const float* __restrict__ bi_e,
    const float* __restrict__ bhn_e, u16* __restrict__ hx,
    float* __restrict__ enc_h,
    const float* __restrict__ eps, const float* __restrict__ Wi_d,
    const float* __restrict__ Wh_d, const float* __restrict__ bhn_d,
    const float* __restrict__ W_shift, const float* __restrict__ b_shift,
    const float* __restrict__ W_lsc, const float* __restrict__ b_lsc,
    const float* __restrict__ W_pi, const float* __restrict__ b_pi,
    const float* __restrict__ W_mu, const float* __restrict__ b_mu,
    const float* __restrict__ W_ls, const float* __restrict__ b_ls,
    const u16* __restrict__ gi2, float* __restrict__ out,
    float* __restrict__ dec_h, float* __restrict__ dec_pred,
    int enc_t0, int dec_t0, int Tc)
{
  const int j = threadIdx.x;
  __shared__ __align__(16) f16 Xp[2][Hn];   // double-buffered packed-f16 h
  __shared__ __align__(16) float nds[Hn];   // n-gate dot (Wh_n . h) per col
  __shared__ float pred_s;
  const int bid = blockIdx.x;
  int cur = 0;
  const bool is_enc = bid < Bn;
  if (is_enc) { if (enc_t0 < 0) return; } else { if (dec_t0 < 0) return; }
  const int b = is_enc ? bid : bid - Bn;
  const int t0 = is_enc ? enc_t0 : dec_t0;
  const float* Wh = is_enc ? Wh_e : Wh_d;

  // ---------------- per-wave persistent register state ----------------
  h2 wa_[64], wb_[64];        // waves0-1: r,z col j | wave2: n cols 2l,2l+1
  float hm = 0.f;
  float bhn = 0, wr0 = 0, wz0 = 0, wn0 = 0;
  float wieR = 0, wieZ = 0, wieN = 0, bieR = 0, bieZ = 0, bieN = 0;
  h2 wp2[32];
  float hbias = 0, predreg = 0;

  if (j < Hn) {
#pragma unroll
    for (int q = 0; q < 64; ++q) {
      h2 a, bq;
      a.x = (f16)Wh[(2 * q) * G3 + j];        a.y = (f16)Wh[(2 * q + 1) * G3 + j];
      bq.x = (f16)Wh[(2 * q) * G3 + 128 + j]; bq.y = (f16)Wh[(2 * q + 1) * G3 + 128 + j];
      wa_[q] = a; wb_[q] = bq;
    }
    if (is_enc) {
      wieR = Wi_e[j]; wieZ = Wi_e[128 + j]; wieN = Wi_e[256 + j];
      bieR = bi_e[j]; bieZ = bi_e[128 + j]; bieN = bi_e[256 + j];
      bhn = bhn_e[j];
      hm = (t0 == 0) ? 0.f : enc_h[(long)b * Hn + j];
    } else {
      wr0 = Wi_d[j]; wz0 = Wi_d[128 + j]; wn0 = Wi_d[256 + j];
      bhn = bhn_d[j];
      hm = (t0 == 0) ? 0.f : dec_h[(long)b * Hn + j];
    }
    Xp[0][j] = (f16)hm;
  } else if (j < 192) {
    const int l = j - 128;              // wave-2 lane: n-gate cols 2l, 2l+1
#pragma unroll
    for (int q = 0; q < 64; ++q) {
      h2 a, bq;
      a.x = (f16)Wh[(2 * q) * G3 + 256 + 2 * l];
      a.y = (f16)Wh[(2 * q + 1) * G3 + 256 + 2 * l];
      bq.x = (f16)Wh[(2 * q) * G3 + 256 + 2 * l + 1];
      bq.y = (f16)Wh[(2 * q + 1) * G3 + 256 + 2 * l + 1];
      wa_[q] = a; wb_[q] = bq;
    }
  } else if (!is_enc) {
    const int lane = j - 192, ho = lane >> 1, hs = lane & 1;
    if (lane < 34) {
#pragma unroll
      for (int q = 0; q < 32; ++q) {
        int ka = 2 * (hs * 32 + q), kb = ka + 1;
        float wva, wvb;
        if (ho == 0) { wva = W_shift[ka]; wvb = W_shift[kb]; }
        else if (ho == 1) { wva = W_lsc[ka]; wvb = W_lsc[kb]; }
        else if (ho < 7) { wva = W_pi[ka * 5 + ho - 2]; wvb = W_pi[kb * 5 + ho - 2]; }
        else if (ho < 12) { wva = W_mu[ka * 5 + ho - 7]; wvb = W_mu[kb * 5 + ho - 7]; }
        else { wva = W_ls[ka * 5 + ho - 12]; wvb = W_ls[kb * 5 + ho - 12]; }
        h2 t; t.x = (f16)wva; t.y = (f16)wvb;
        wp2[q] = t;
      }
      hbias = (ho == 0) ? b_shift[0] : (ho == 1) ? b_lsc[0] : (ho < 7) ? b_pi[ho - 2]
            : (ho < 12) ? b_mu[ho - 7] : b_ls[ho - 12];
    } else {
#pragma unroll
      for (int q = 0; q < 32; ++q) { h2 t; t.x = (f16)0.f; t.y = (f16)0.f; wp2[q] = t; }
    }
    predreg = (t0 == 0) ? 0.f : dec_pred[b];
    if (lane == 0) pred_s = predreg;
  }
  __syncthreads();

  const float* xrow = x + (long)b * Tn;
  const float* erow = eps + (long)b * Tn;
  const u16* gibase = gi2 + (long)b * G3 * Tc;
  u16* hxrow = hx + ((long)b * Hn + (j < Hn ? j : 0)) * Tc;
  float* outlp = out + (long)b * Tn + t0;
  float* outpr = out + (long)Bn * Tn + (long)b * Tn + t0;
  const int lane3 = j - 192;
  float ep = 0.f;
  float lp0 = 0, lp1 = 0, lp2 = 0, lp3 = 0, lp4 = 0, lp5 = 0, lp6 = 0, lp7 = 0;
  float pr0 = 0, pr1 = 0, pr2 = 0, pr3 = 0, pr4 = 0, pr5 = 0, pr6 = 0, pr7 = 0;

  // heads + coupling on wave 3 for h in Xc; result valid on lane3 0.
  auto couple = [&](float e, const f16* Xc) -> float2 {
    const int hs = lane3 & 1;
    float p = 0.f;
    if (lane3 < 34) {
      const uint4* hp4 = (const uint4*)Xc;
#pragma unroll
      for (int q = 0; q < 8; ++q) {
        uint4 hv = hp4[hs * 8 + q];
        p = fdot2f(bch2(hv.x), wp2[4 * q + 0], p);
        p = fdot2f(bch2(hv.y), wp2[4 * q + 1], p);
        p = fdot2f(bch2(hv.z), wp2[4 * q + 2], p);
        p = fdot2f(bch2(hv.w), wp2[4 * q + 3], p);
      }
    }
    p += __shfl_xor(p, 1);
    float pb = p + hbias;
    const int lj2 = lane3 & 7;
    float pi_ = __shfl(pb, 4 + 2 * lj2);
    float mu_ = __shfl(pb, 14 + 2 * lj2);
    float ls_ = __shfl(pb, 24 + 2 * lj2);
    float shiftv = __shfl(pb, 0);
    float lscv = __shfl(pb, 2);
    const bool valid = (lane3 < 5);
    float wexp = valid ? __expf(pi_) : 0.f;
    float zz = (e - mu_) * __expf(-ls_);
    float uq = __expf(-fabsf(zz));
    float dq = 1.f / (1.f + uq);
    float sigp = (zz >= 0.f) ? dq : uq * dq;
    float sigq = (zz >= 0.f) ? uq * dq : dq;
    float pdfl = uq * dq * dq * __expf(-ls_);
    float c = wexp * sigp, m = wexp * sigq, pq = wexp * pdfl, S = wexp;
    c += __shfl_xor(c, 1, 8); m += __shfl_xor(m, 1, 8);
    pq += __shfl_xor(pq, 1, 8); S += __shfl_xor(S, 1, 8);
    c += __shfl_xor(c, 2, 8); m += __shfl_xor(m, 2, 8);
    pq += __shfl_xor(pq, 2, 8); S += __shfl_xor(S, 2, 8);
    c += __shfl_xor(c, 4, 8); m += __shfl_xor(m, 4, 8);
    pq += __shfl_xor(pq, 4, 8); S += __shfl_xor(S, 4, 8);
    float logc = __logf(c), logm = __logf(m);
    float val = logc - logm;
    float ljac = __logf(pq) + __logf(S) - logc - logm;
    float prednew = fmaf(val, __expf(lscv), shiftv);
    float sp = fmaxf(-e, 0.f) + log1pf(__expf(-fabsf(e)));
    float logp = (-e - 2.f * sp) - lscv - ljac;
    return make_float2(logp, prednew);
  };

  // -------- group-0 global batch (current regs) --------
  uint4 gR4 = {0, 0, 0, 0}, gZ4 = {0, 0, 0, 0}, gN4 = {0, 0, 0, 0};
  float4 xv0 = {0, 0, 0, 0}, xv1 = {0, 0, 0, 0};
  float4 ev0 = {0, 0, 0, 0}, ev1 = {0, 0, 0, 0};
  if (j < Hn) {
    if (is_enc) {
      int base = Tn - 8 - t0; if (base < 0) base = 0;
      xv0 = *(const float4*)(xrow + base);
      xv1 = *(const float4*)(xrow + base + 4);
    } else {
      gR4 = *(const uint4*)(gibase + (long)j * Tc);
      gZ4 = *(const uint4*)(gibase + (long)(128 + j) * Tc);
      gN4 = *(const uint4*)(gibase + (long)(256 + j) * Tc);
    }
  } else if (j >= 192 && !is_enc) {
    ev0 = *(const float4*)(erow + t0);
    ev1 = *(const float4*)(erow + t0 + 4);
  }

  for (int i8 = 0; i8 < Tc; i8 += 8) {
    // -------- unpack current batch; issue NEXT group's loads (8-slot slack) --------
    uint4 gRn = {0, 0, 0, 0}, gZn = {0, 0, 0, 0}, gNn = {0, 0, 0, 0};
    float4 xn0 = {0, 0, 0, 0}, xn1 = {0, 0, 0, 0};
    float4 en0 = {0, 0, 0, 0}, en1 = {0, 0, 0, 0};
    float xc0 = 0, xc1 = 0, xc2 = 0, xc3 = 0, xc4 = 0, xc5 = 0, xc6 = 0, xc7 = 0;
    float ec0 = 0, ec1 = 0, ec2 = 0, ec3 = 0, ec4 = 0, ec5 = 0, ec6 = 0, ec7 = 0;
    u32 hb0 = 0, hb1 = 0, hb2 = 0, hb3 = 0;
    if (j < Hn) {
      if (is_enc) {
        xc0 = xv1.w; xc1 = xv1.z; xc2 = xv1.y; xc3 = xv1.x;
        xc4 = xv0.w; xc5 = xv0.z; xc6 = xv0.y; xc7 = xv0.x;
        int nb = Tn - 8 - t0 - (i8 + 8); if (nb < 0) nb = 0;
        xn0 = *(const float4*)(xrow + nb);
        xn1 = *(const float4*)(xrow + nb + 4);
      } else {
        int gn = i8 + 8; if (gn > Tc - 8) gn = Tc - 8;
        gRn = *(const uint4*)(gibase + (long)j * Tc + gn);
        gZn = *(const uint4*)(gibase + (long)(128 + j) * Tc + gn);
        gNn = *(const uint4*)(gibase + (long)(256 + j) * Tc + gn);
      }
    } else if (j >= 192 && !is_enc) {
      ec0 = ev0.x; ec1 = ev0.y; ec2 = ev0.z; ec3 = ev0.w;
      ec4 = ev1.x; ec5 = ev1.y; ec6 = ev1.z; ec7 = ev1.w;
      int sn = t0 + i8 + 8; if (sn > Tn - 8) sn = Tn - 8;
      en0 = *(const float4*)(erow + sn);
      en1 = *(const float4*)(erow + sn + 4);
    }
#pragma unroll
    for (int u = 0; u < 8; ++u) {
      const int i = i8 + u;
      float ar = 0, az = 0;
      // ----------------- P1 -----------------
      if (j < Hn) {
        const uint4* hp = (const uint4*)Xp[cur];
        float a0r = 0, a1r = 0, a0z = 0, a1z = 0;
#pragma unroll
        for (int q = 0; q < 16; ++q) {
          uint4 hv = hp[q];
          a0r = fdot2f(bch2(hv.x), wa_[4 * q + 0], a0r);
          a1r = fdot2f(bch2(hv.y), wa_[4 * q + 1], a1r);
          a0r = fdot2f(bch2(hv.z), wa_[4 * q + 2], a0r);
          a1r = fdot2f(bch2(hv.w), wa_[4 * q + 3], a1r);
          a0z = fdot2f(bch2(hv.x), wb_[4 * q + 0], a0z);
          a1z = fdot2f(bch2(hv.y), wb_[4 * q + 1], a1z);
          a0z = fdot2f(bch2(hv.z), wb_[4 * q + 2], a0z);
          a1z = fdot2f(bch2(hv.w), wb_[4 * q + 3], a1z);
        }
        ar = a0r + a1r; az = a0z + a1z;
      } else if (j < 192) {
        const int l = j - 128;
        const uint4* hp = (const uint4*)Xp[cur];
        float a0 = 0, a1 = 0, b0 = 0, b1 = 0;
#pragma unroll
        for (int q = 0; q < 16; ++q) {
          uint4 hv = hp[q];
          a0 = fdot2f(bch2(hv.x), wa_[4 * q + 0], a0);
          a1 = fdot2f(bch2(hv.y), wa_[4 * q + 1], a1);
          a0 = fdot2f(bch2(hv.z), wa_[4 * q + 2], a0);
          a1 = fdot2f(bch2(hv.w), wa_[4 * q + 3], a1);
          b0 = fdot2f(bch2(hv.x), wb_[4 * q + 0], b0);
          b1 = fdot2f(bch2(hv.y), wb_[4 * q + 1], b1);
          b0 = fdot2f(bch2(hv.z), wb_[4 * q + 2], b0);
          b1 = fdot2f(bch2(hv.w), wb_[4 * q + 3], b1);
        }
        float2 nv; nv.x = a0 + a1; nv.y = b0 + b1;
        *(float2*)&nds[2 * l] = nv;
      } else if (!is_enc && i >= 1) {
        float e = (u == 0) ? ep : (u == 1) ? ec0 : (u == 2) ? ec1 : (u == 3) ? ec2
                : (u == 4) ? ec3 : (u == 5) ? ec4 : (u == 6) ? ec5 : ec6;
        float2 rr = couple(e, Xp[cur]);
        if (lane3 == 0) {
          if (u == 0) { lp7 = rr.x; pr7 = rr.y; }
          else if (u == 1) { lp0 = rr.x; pr0 = rr.y; }
          else if (u == 2) { lp1 = rr.x; pr1 = rr.y; }
          else if (u == 3) { lp2 = rr.x; pr2 = rr.y; }
          else if (u == 4) { lp3 = rr.x; pr3 = rr.y; }
          else if (u == 5) { lp4 = rr.x; pr4 = rr.y; }
          else if (u == 6) { lp5 = rr.x; pr5 = rr.y; }
          else { lp6 = rr.x; pr6 = rr.y; }
          pred_s = rr.y;
          predreg = rr.y;
          if (u == 0 && i8 > 0) {
            *(float4*)(outlp + i8 - 8) = make_float4(lp0, lp1, lp2, lp3);
            *(float4*)(outlp + i8 - 4) = make_float4(lp4, lp5, lp6, lp7);
            *(float4*)(outpr + i8 - 8) = make_float4(pr0, pr1, pr2, pr3);
            *(float4*)(outpr + i8 - 4) = make_float4(pr4, pr5, pr6, pr7);
          }
        }
      }
      __syncthreads();                                 // B1: nds + pred_s ready
      // ----------------- P2: gates -----------------
      if (j < Hn) {
        float nd = nds[j];
        float gir, giz, gin;
        if (is_enc) {
          const float xt = (u == 0) ? xc0 : (u == 1) ? xc1 : (u == 2) ? xc2
                          : (u == 3) ? xc3 : (u == 4) ? xc4 : (u == 5) ? xc5
                          : (u == 6) ? xc6 : xc7;
          gir = fmaf(xt, wieR, bieR);
          giz = fmaf(xt, wieZ, bieZ);
          gin = fmaf(xt, wieN, bieN);
        } else {
          u16 gvr = (u == 0) ? (u16)gR4.x : (u == 1) ? (u16)(gR4.x >> 16)
                  : (u == 2) ? (u16)gR4.y : (u == 3) ? (u16)(gR4.y >> 16)
                  : (u == 4) ? (u16)gR4.z : (u == 5) ? (u16)(gR4.z >> 16)
                  : (u == 6) ? (u16)gR4.w : (u16)(gR4.w >> 16);
          u16 gvz = (u == 0) ? (u16)gZ4.x : (u == 1) ? (u16)(gZ4.x >> 16)
                  : (u == 2) ? (u16)gZ4.y : (u == 3) ? (u16)(gZ4.y >> 16)
                  : (u == 4) ? (u16)gZ4.z : (u == 5) ? (u16)(gZ4.z >> 16)
                  : (u == 6) ? (u16)gZ4.w : (u16)(gZ4.w >> 16);
          u16 gvn = (u == 0) ? (u16)gN4.x : (u == 1) ? (u16)(gN4.x >> 16)
                  : (u == 2) ? (u16)gN4.y : (u == 3) ? (u16)(gN4.y >> 16)
                  : (u == 4) ? (u16)gN4.z : (u == 5) ? (u16)(gN4.z >> 16)
                  : (u == 6) ? (u16)gN4.w : (u16)(gN4.w >> 16);
          float pred = pred_s;
          gir = h2f(gvr) + pred * wr0;
          giz = h2f(gvz) + pred * wz0;
          gin = h2f(gvn) + pred * wn0;
        }
        float r = sigm(ar + gir);
        float z = sigm(az + giz);
        float n = tanh_fast(gin + r * (nd + bhn));
        hm = (1.f - z) * n + z * hm;
        Xp[cur ^ 1][j] = (f16)hm;
        if (is_enc) {
          u16 hv16 = f2h(hm);
          if (u == 0) hb0 = hv16; else if (u == 1) hb0 |= ((u32)hv16 << 16);
          else if (u == 2) hb1 = hv16; else if (u == 3) hb1 |= ((u32)hv16 << 16);
          else if (u == 4) hb2 = hv16; else if (u == 5) hb2 |= ((u32)hv16 << 16);
          else if (u == 6) hb3 = hv16; else hb3 |= ((u32)hv16 << 16);
        }
      }
      __syncthreads();                                 // B2: Xp(next) ready
      cur ^= 1;
    }
    if (is_enc && j < Hn) {
      uint4 o; o.x = hb0; o.y = hb1; o.z = hb2; o.w = hb3;
      *(uint4*)(hxrow + i8) = o;
    }
    // -------- rotate group batches --------
    gR4 = gRn; gZ4 = gZn; gN4 = gNn;
    xv0 = xn0; xv1 = xn1;
    if (!is_enc && j >= 192) { ep = ec7; ev0 = en0; ev1 = en1; }
  }
  // trailing couple for step Tc-1 + final batch store
  if (!is_enc && j >= 192) {
    float2 rr = couple(ep, Xp[cur]);
    if (lane3 == 0) {
      lp7 = rr.x; pr7 = rr.y; predreg = rr.y;
      *(float4*)(outlp + Tc - 8) = make_float4(lp0, lp1, lp2, lp3);
      *(float4*)(outlp + Tc - 4) = make_float4(lp4, lp5, lp6, lp7);
      *(float4*)(outpr + Tc - 8) = make_float4(pr0, pr1, pr2, pr3);
      *(float4*)(outpr + Tc - 4) = make_float4(pr4, pr5, pr6, pr7);
    }
  }
  if (j < Hn) (is_enc ? enc_h : dec_h)[(long)b * Hn + j] = hm;
  if (!is_enc && j == 192) dec_pred[b] = predreg;
}

// ---- GEMM: gi2[b][col][t] = hx[b][:][t]^T @ Wi_d[1:,:] + bi_d  (fp32 acc) ----
// A2 layout: [b][k][tt] ; C2 layout: [b][col][tt]  (both f16, t contiguous)
__global__ __launch_bounds__(256) void gemm_gi(
    const u16* __restrict__ A2, const float* __restrict__ Wi_d,
    const float* __restrict__ bi_d, u16* __restrict__ C2, int Tc)
{
  __shared__ __align__(16) float As[16][64];  // [k][m]
  __shared__ __align__(16) float Ws[16][64];  // [k][n]
  const int tid = threadIdx.x;
  const long m0 = (long)blockIdx.x * 64;      // m = b*Tc + tt
  const int n0 = blockIdx.y * 64;
  const int bb = (int)(m0 / Tc);
  const int tt0 = (int)(m0 - (long)bb * Tc);
  const int tx = tid & 15, ty = tid >> 4;
  const int lk = tid >> 4, lm = (tid & 15) * 4;   // A-load: k row, 4 tt's
  const int wk = tid >> 4, wn = (tid & 15) * 4;
  float acc[4][4] = {};
  for (int k0 = 0; k0 < Hn; k0 += 16) {
    uint2 a2v = *(const uint2*)(A2 + ((long)bb * Hn + k0 + lk) * Tc + tt0 + lm);
    float4 w4 = *(const float4*)(Wi_d + (long)(1 + k0 + wk) * G3 + n0 + wn);
    __syncthreads();
    As[lk][lm + 0] = h2f((u16)(a2v.x & 0xffffu));
    As[lk][lm + 1] = h2f((u16)(a2v.x >> 16));
    As[lk][lm + 2] = h2f((u16)(a2v.y & 0xffffu));
    As[lk][lm + 3] = h2f((u16)(a2v.y >> 16));
    *(float4*)&Ws[wk][wn] = w4;
    __syncthreads();
#pragma unroll
    for (int kk = 0; kk < 16; ++kk) {
      float4 av = *(const float4*)&As[kk][ty * 4];
      float4 wv = *(const float4*)&Ws[kk][tx * 4];
      float ar[4] = {av.x, av.y, av.z, av.w};
      float wr[4] = {wv.x, wv.y, wv.z, wv.w};
#pragma unroll
      for (int i = 0; i < 4; ++i)
#pragma unroll
        for (int jj = 0; jj < 4; ++jj) acc[i][jj] = fmaf(ar[i], wr[jj], acc[i][jj]);
    }
  }
  const float4 bbv = *(const float4*)(bi_d + n0 + tx * 4);
  const float br[4] = {bbv.x, bbv.y, bbv.z, bbv.w};
#pragma unroll
  for (int jj = 0; jj < 4; ++jj) {
    int colc = n0 + tx * 4 + jj;
    u32 lo = (u32)f2h(acc[0][jj] + br[jj]) | ((u32)f2h(acc[1][jj] + br[jj]) << 16);
    u32 hi = (u32)f2h(acc[2][jj] + br[jj]) | ((u32)f2h(acc[3][jj] + br[jj]) << 16);
    uint2 o; o.x = lo; o.y = hi;
    *(uint2*)(C2 + ((long)bb * G3 + colc) * Tc + tt0 + ty * 4) = o;
  }
}

extern "C" void kernel_launch(void* const* d_in, const int* in_sizes, int n_in,
                              void* d_out, int out_size, void* d_ws, size_t ws_size,
                              hipStream_t stream) {
  const float* x = (const float*)d_in[1];
  const float* eps = (const float*)d_in[2];
  const float* Wi_e = (const float*)d_in[3];
  const float* Wh_e = (const float*)d_in[4];
  const float* bi_e = (const float*)d_in[5];
  const float* bhn_e = (const float*)d_in[6];
  const float* Wi_d = (const float*)d_in[7];
  const float* Wh_d = (const float*)d_in[8];
  const float* bi_d = (const float*)d_in[9];
  const float* bhn_d = (const float*)d_in[10];
  const float* W_shift = (const float*)d_in[11];
  const float* b_shift = (const float*)d_in[12];
  const float* W_lsc = (const float*)d_in[13];
  const float* b_lsc = (const float*)d_in[14];
  const float* W_pi = (const float*)d_in[15];
  const float* b_pi = (const float*)d_in[16];
  const float* W_mu = (const float*)d_in[17];
  const float* b_mu = (const float*)d_in[18];
  const float* W_ls = (const float*)d_in[19];
  const float* b_ls = (const float*)d_in[20];
  float* out = (float*)d_out;

  const size_t stateB = (size_t)(2 * Bn * Hn + Bn) * sizeof(float);
  const size_t stateAl = (stateB + 255) & ~(size_t)255;
  int Tc = 256;  // 16 chunks: smaller pipeline-fill cost (total slots Tn+Tc)
  while (Tc > 64 && stateAl + (size_t)Bn * Tc * (Hn + G3) * 2 > ws_size) Tc >>= 1;
  if (stateAl + (size_t)Bn * Tc * (Hn + G3) * 2 > ws_size) return;

  float* enc_h = (float*)d_ws;
  float* dec_h = enc_h + (size_t)Bn * Hn;
  float* dec_pred = dec_h + (size_t)Bn * Hn;
  u16* hx = (u16*)((char*)d_ws + stateAl);          // [b][k][t]
  u16* gi = hx + (size_t)Bn * Tc * Hn;              // [b][col][t]

  const int Nc = Tn / Tc;
  const dim3 gg((unsigned)(((size_t)Bn * Tc) / 64), G3 / 64);
  for (int k = 0; k <= Nc; ++k) {
    int enc_t0 = (k < Nc) ? k * Tc : -1;
    int dec_t0 = (k >= 1) ? (k - 1) * Tc : -1;
    combo_kernel<<<2 * Bn, NTH, 0, stream>>>(
        x, Wi_e, Wh_e, bi_e, bhn_e, hx, enc_h,
        eps, Wi_d, Wh_d, bhn_d, W_shift, b_shift, W_lsc, b_lsc,
        W_pi, b_pi, W_mu, b_mu, W_ls, b_ls,
        gi, out, dec_h, dec_pred, enc_t0, dec_t0, Tc);
    if (k < Nc) gemm_gi<<<gg, 256, 0, stream>>>(hx, Wi_d, bi_d, gi, Tc);
  }
}

// Round 13
// 5642.064 us; speedup vs baseline: 1.0188x; 1.0188x over previous
//
#include <hip/hip_runtime.h>
#include <hip/hip_fp16.h>

#define Tn 4096
#define Bn 128
#define Hn 128
#define G3 384
#define NTH 256  // 4 waves: 0-1 r/z matvec+gates, 2 n-matvec, 3 heads+coupling

typedef unsigned short u16;
typedef unsigned int u32;
typedef _Float16 f16;
typedef _Float16 h2 __attribute__((ext_vector_type(2)));

__device__ __forceinline__ float sigm(float v) { return 1.f / (1.f + __expf(-v)); }
__device__ __forceinline__ float tanh_fast(float v) {
  v = fminf(fmaxf(v, -15.f), 15.f);
  float e = __expf(-2.f * v);
  return (1.f - e) / (1.f + e);
}
__device__ __forceinline__ u16 f2h(float f) { return __half_as_ushort(__float2half(f)); }
__device__ __forceinline__ float h2f(u16 u) { return __half2float(__ushort_as_half(u)); }
__device__ __forceinline__ h2 bch2(u32 v) { union { u32 u; h2 h; } t; t.u = v; return t.h; }
__device__ __forceinline__ float fdot2f(h2 a, h2 b, float c) {
  return __builtin_amdgcn_fdot2(a, b, c, false);
}

// ============ combo: blocks 0..127 = encoder, 128..255 = decoder ============
// Per-thread weight footprint capped at 128 VGPRs (r/z on waves 0-1, n on
// wave 2); nds[] carries the n-gate dot from wave 2 to the gate threads.
// couple() uses 4 independent accumulator chains to cut dependent latency.
__global__ __launch_bounds__(NTH, 1) void combo_kernel(
    const float* __restrict__ x, const float* __restrict__ Wi_e,
    const float* __restrict__ Wh_e, const float* __restrict__ bi_e,
    const float* __restrict__ bhn_e, u16* __restrict__ hx,
    float* __restrict__ enc_h,
    const float* __restrict__ eps, const float* __restrict__ Wi_d,
    const float* __restrict__ Wh_d, const float* __restrict__ bhn_d,
    const float* __restrict__ W_shift, const float* __restrict__ b_shift,
    const float* __restrict__ W_lsc, const float* __restrict__ b_lsc,
    const float* __restrict__ W_pi, const float* __restrict__ b_pi,
    const float* __restrict__ W_mu, const float* __restrict__ b_mu,
    const float* __restrict__ W_ls, const float* __restrict__ b_ls,
    const u16* __restrict__ gi2, float* __restrict__ out,
    float* __restrict__ dec_h, float* __restrict__ dec_pred,
    int enc_t0, int dec_t0, int Tc)
{
  const int j = threadIdx.x;
  __shared__ __align__(16) f16 Xp[2][Hn];   // double-buffered packed-f16 h
  __shared__ __align__(16) float nds[Hn];   // n-gate dot (Wh_n . h) per col
  __shared__ float pred_s;
  const int bid = blockIdx.x;
  int cur = 0;
  const bool is_enc = bid < Bn;
  if (is_enc) { if (enc_t0 < 0) return; } else { if (dec_t0 < 0) return; }
  const int b = is_enc ? bid : bid - Bn;
  const int t0 = is_enc ? enc_t0 : dec_t0;
  const float* Wh = is_enc ? Wh_e : Wh_d;

  // ---------------- per-wave persistent register state ----------------
  h2 wa_[64], wb_[64];        // waves0-1: r,z col j | wave2: n cols 2l,2l+1
  float hm = 0.f;
  float bhn = 0, wr0 = 0, wz0 = 0, wn0 = 0;
  float wieR = 0, wieZ = 0, wieN = 0, bieR = 0, bieZ = 0, bieN = 0;
  h2 wp2[32];
  float hbias = 0, predreg = 0;

  if (j < Hn) {
#pragma unroll
    for (int q = 0; q < 64; ++q) {
      h2 a, bq;
      a.x = (f16)Wh[(2 * q) * G3 + j];        a.y = (f16)Wh[(2 * q + 1) * G3 + j];
      bq.x = (f16)Wh[(2 * q) * G3 + 128 + j]; bq.y = (f16)Wh[(2 * q + 1) * G3 + 128 + j];
      wa_[q] = a; wb_[q] = bq;
    }
    if (is_enc) {
      wieR = Wi_e[j]; wieZ = Wi_e[128 + j]; wieN = Wi_e[256 + j];
      bieR = bi_e[j]; bieZ = bi_e[128 + j]; bieN = bi_e[256 + j];
      bhn = bhn_e[j];
      hm = (t0 == 0) ? 0.f : enc_h[(long)b * Hn + j];
    } else {
      wr0 = Wi_d[j]; wz0 = Wi_d[128 + j]; wn0 = Wi_d[256 + j];
      bhn = bhn_d[j];
      hm = (t0 == 0) ? 0.f : dec_h[(long)b * Hn + j];
    }
    Xp[0][j] = (f16)hm;
  } else if (j < 192) {
    const int l = j - 128;              // wave-2 lane: n-gate cols 2l, 2l+1
#pragma unroll
    for (int q = 0; q < 64; ++q) {
      h2 a, bq;
      a.x = (f16)Wh[(2 * q) * G3 + 256 + 2 * l];
      a.y = (f16)Wh[(2 * q + 1) * G3 + 256 + 2 * l];
      bq.x = (f16)Wh[(2 * q) * G3 + 256 + 2 * l + 1];
      bq.y = (f16)Wh[(2 * q + 1) * G3 + 256 + 2 * l + 1];
      wa_[q] = a; wb_[q] = bq;
    }
  } else if (!is_enc) {
    const int lane = j - 192, ho = lane >> 1, hs = lane & 1;
    if (lane < 34) {
#pragma unroll
      for (int q = 0; q < 32; ++q) {
        int ka = 2 * (hs * 32 + q), kb = ka + 1;
        float wva, wvb;
        if (ho == 0) { wva = W_shift[ka]; wvb = W_shift[kb]; }
        else if (ho == 1) { wva = W_lsc[ka]; wvb = W_lsc[kb]; }
        else if (ho < 7) { wva = W_pi[ka * 5 + ho - 2]; wvb = W_pi[kb * 5 + ho - 2]; }
        else if (ho < 12) { wva = W_mu[ka * 5 + ho - 7]; wvb = W_mu[kb * 5 + ho - 7]; }
        else { wva = W_ls[ka * 5 + ho - 12]; wvb = W_ls[kb * 5 + ho - 12]; }
        h2 t; t.x = (f16)wva; t.y = (f16)wvb;
        wp2[q] = t;
      }
      hbias = (ho == 0) ? b_shift[0] : (ho == 1) ? b_lsc[0] : (ho < 7) ? b_pi[ho - 2]
            : (ho < 12) ? b_mu[ho - 7] : b_ls[ho - 12];
    } else {
#pragma unroll
      for (int q = 0; q < 32; ++q) { h2 t; t.x = (f16)0.f; t.y = (f16)0.f; wp2[q] = t; }
    }
    predreg = (t0 == 0) ? 0.f : dec_pred[b];
    if (lane == 0) pred_s = predreg;
  }
  __syncthreads();

  const float* xrow = x + (long)b * Tn;
  const float* erow = eps + (long)b * Tn;
  const u16* gibase = gi2 + (long)b * G3 * Tc;
  u16* hxrow = hx + ((long)b * Hn + (j < Hn ? j : 0)) * Tc;
  float* outlp = out + (long)b * Tn + t0;
  float* outpr = out + (long)Bn * Tn + (long)b * Tn + t0;
  const int lane3 = j - 192;
  float ep = 0.f;
  float lp0 = 0, lp1 = 0, lp2 = 0, lp3 = 0, lp4 = 0, lp5 = 0, lp6 = 0, lp7 = 0;
  float pr0 = 0, pr1 = 0, pr2 = 0, pr3 = 0, pr4 = 0, pr5 = 0, pr6 = 0, pr7 = 0;

  // heads + coupling on wave 3 for h in Xc; result valid on lane3 0.
  // 4 independent fdot2 chains (dependent-latency ~4x shorter than 1 chain).
  auto couple = [&](float e, const f16* Xc) -> float2 {
    const int hs = lane3 & 1;
    float p0 = 0.f, p1 = 0.f, p2 = 0.f, p3 = 0.f;
    if (lane3 < 34) {
      const uint4* hp4 = (const uint4*)Xc;
#pragma unroll
      for (int q = 0; q < 8; ++q) {
        uint4 hv = hp4[hs * 8 + q];
        p0 = fdot2f(bch2(hv.x), wp2[4 * q + 0], p0);
        p1 = fdot2f(bch2(hv.y), wp2[4 * q + 1], p1);
        p2 = fdot2f(bch2(hv.z), wp2[4 * q + 2], p2);
        p3 = fdot2f(bch2(hv.w), wp2[4 * q + 3], p3);
      }
    }
    float p = (p0 + p1) + (p2 + p3);
    p += __shfl_xor(p, 1);
    float pb = p + hbias;
    const int lj2 = lane3 & 7;
    float pi_ = __shfl(pb, 4 + 2 * lj2);
    float mu_ = __shfl(pb, 14 + 2 * lj2);
    float ls_ = __shfl(pb, 24 + 2 * lj2);
    float shiftv = __shfl(pb, 0);
    float lscv = __shfl(pb, 2);
    const bool valid = (lane3 < 5);
    float wexp = valid ? __expf(pi_) : 0.f;
    float zz = (e - mu_) * __expf(-ls_);
    float uq = __expf(-fabsf(zz));
    float dq = 1.f / (1.f + uq);
    float sigp = (zz >= 0.f) ? dq : uq * dq;
    float sigq = (zz >= 0.f) ? uq * dq : dq;
    float pdfl = uq * dq * dq * __expf(-ls_);
    float c = wexp * sigp, m = wexp * sigq, pq = wexp * pdfl, S = wexp;
    c += __shfl_xor(c, 1, 8); m += __shfl_xor(m, 1, 8);
    pq += __shfl_xor(pq, 1, 8); S += __shfl_xor(S, 1, 8);
    c += __shfl_xor(c, 2, 8); m += __shfl_xor(m, 2, 8);
    pq += __shfl_xor(pq, 2, 8); S += __shfl_xor(S, 2, 8);
    c += __shfl_xor(c, 4, 8); m += __shfl_xor(m, 4, 8);
    pq += __shfl_xor(pq, 4, 8); S += __shfl_xor(S, 4, 8);
    float logc = __logf(c), logm = __logf(m);
    float val = logc - logm;
    float ljac = __logf(pq) + __logf(S) - logc - logm;
    float prednew = fmaf(val, __expf(lscv), shiftv);
    float sp = fmaxf(-e, 0.f) + log1pf(__expf(-fabsf(e)));
    float logp = (-e - 2.f * sp) - lscv - ljac;
    return make_float2(logp, prednew);
  };

  for (int i8 = 0; i8 < Tc; i8 += 8) {
    // -------- per-8-slot batched global I/O --------
    uint4 gR4 = {0, 0, 0, 0}, gZ4 = {0, 0, 0, 0}, gN4 = {0, 0, 0, 0};
    float xc0 = 0, xc1 = 0, xc2 = 0, xc3 = 0, xc4 = 0, xc5 = 0, xc6 = 0, xc7 = 0;
    float ec0 = 0, ec1 = 0, ec2 = 0, ec3 = 0, ec4 = 0, ec5 = 0, ec6 = 0, ec7 = 0;
    u32 hb0 = 0, hb1 = 0, hb2 = 0, hb3 = 0;
    if (j < Hn) {
      if (is_enc) {
        int base = Tn - 8 - t0 - i8; if (base < 0) base = 0;
        float4 v0 = *(const float4*)(xrow + base);
        float4 v1 = *(const float4*)(xrow + base + 4);
        xc0 = v1.w; xc1 = v1.z; xc2 = v1.y; xc3 = v1.x;
        xc4 = v0.w; xc5 = v0.z; xc6 = v0.y; xc7 = v0.x;
      } else {
        gR4 = *(const uint4*)(gibase + (long)j * Tc + i8);
        gZ4 = *(const uint4*)(gibase + (long)(128 + j) * Tc + i8);
        gN4 = *(const uint4*)(gibase + (long)(256 + j) * Tc + i8);
      }
    } else if (j >= 192 && !is_enc) {
      float4 v0 = *(const float4*)(erow + t0 + i8);
      float4 v1 = *(const float4*)(erow + t0 + i8 + 4);
      ec0 = v0.x; ec1 = v0.y; ec2 = v0.z; ec3 = v0.w;
      ec4 = v1.x; ec5 = v1.y; ec6 = v1.z; ec7 = v1.w;
    }
#pragma unroll
    for (int u = 0; u < 8; ++u) {
      const int i = i8 + u;
      float ar = 0, az = 0;
      // ----------------- P1 -----------------
      if (j < Hn) {
        const uint4* hp = (const uint4*)Xp[cur];
        float a0r = 0, a1r = 0, a0z = 0, a1z = 0;
#pragma unroll
        for (int q = 0; q < 16; ++q) {
          uint4 hv = hp[q];
          a0r = fdot2f(bch2(hv.x), wa_[4 * q + 0], a0r);
          a1r = fdot2f(bch2(hv.y), wa_[4 * q + 1], a1r);
          a0r = fdot2f(bch2(hv.z), wa_[4 * q + 2], a0r);
          a1r = fdot2f(bch2(hv.w), wa_[4 * q + 3], a1r);
          a0z = fdot2f(bch2(hv.x), wb_[4 * q + 0], a0z);
          a1z = fdot2f(bch2(hv.y), wb_[4 * q + 1], a1z);
          a0z = fdot2f(bch2(hv.z), wb_[4 * q + 2], a0z);
          a1z = fdot2f(bch2(hv.w), wb_[4 * q + 3], a1z);
        }
        ar = a0r + a1r; az = a0z + a1z;
      } else if (j < 192) {
        const int l = j - 128;
        const uint4* hp = (const uint4*)Xp[cur];
        float a0 = 0, a1 = 0, b0 = 0, b1 = 0;
#pragma unroll
        for (int q = 0; q < 16; ++q) {
          uint4 hv = hp[q];
          a0 = fdot2f(bch2(hv.x), wa_[4 * q + 0], a0);
          a1 = fdot2f(bch2(hv.y), wa_[4 * q + 1], a1);
          a0 = fdot2f(bch2(hv.z), wa_[4 * q + 2], a0);
          a1 = fdot2f(bch2(hv.w), wa_[4 * q + 3], a1);
          b0 = fdot2f(bch2(hv.x), wb_[4 * q + 0], b0);
          b1 = fdot2f(bch2(hv.y), wb_[4 * q + 1], b1);
          b0 = fdot2f(bch2(hv.z), wb_[4 * q + 2], b0);
          b1 = fdot2f(bch2(hv.w), wb_[4 * q + 3], b1);
        }
        float2 nv; nv.x = a0 + a1; nv.y = b0 + b1;
        *(float2*)&nds[2 * l] = nv;
      } else if (!is_enc && i >= 1) {
        float e = (u == 0) ? ep : (u == 1) ? ec0 : (u == 2) ? ec1 : (u == 3) ? ec2
                : (u == 4) ? ec3 : (u == 5) ? ec4 : (u == 6) ? ec5 : ec6;
        float2 rr = couple(e, Xp[cur]);
        if (lane3 == 0) {
          if (u == 0) { lp7 = rr.x; pr7 = rr.y; }
          else if (u == 1) { lp0 = rr.x; pr0 = rr.y; }
          else if (u == 2) { lp1 = rr.x; pr1 = rr.y; }
          else if (u == 3) { lp2 = rr.x; pr2 = rr.y; }
          else if (u == 4) { lp3 = rr.x; pr3 = rr.y; }
          else if (u == 5) { lp4 = rr.x; pr4 = rr.y; }
          else if (u == 6) { lp5 = rr.x; pr5 = rr.y; }
          else { lp6 = rr.x; pr6 = rr.y; }
          pred_s = rr.y;
          predreg = rr.y;
          if (u == 0 && i8 > 0) {
            *(float4*)(outlp + i8 - 8) = make_float4(lp0, lp1, lp2, lp3);
            *(float4*)(outlp + i8 - 4) = make_float4(lp4, lp5, lp6, lp7);
            *(float4*)(outpr + i8 - 8) = make_float4(pr0, pr1, pr2, pr3);
            *(float4*)(outpr + i8 - 4) = make_float4(pr4, pr5, pr6, pr7);
          }
        }
      }
      __syncthreads();                                 // B1: nds + pred_s ready
      // ----------------- P2: gates -----------------
      if (j < Hn) {
        float nd = nds[j];
        float gir, giz, gin;
        if (is_enc) {
          const float xt = (u == 0) ? xc0 : (u == 1) ? xc1 : (u == 2) ? xc2
                          : (u == 3) ? xc3 : (u == 4) ? xc4 : (u == 5) ? xc5
                          : (u == 6) ? xc6 : xc7;
          gir = fmaf(xt, wieR, bieR);
          giz = fmaf(xt, wieZ, bieZ);
          gin = fmaf(xt, wieN, bieN);
        } else {
          u16 gvr = (u == 0) ? (u16)gR4.x : (u == 1) ? (u16)(gR4.x >> 16)
                  : (u == 2) ? (u16)gR4.y : (u == 3) ? (u16)(gR4.y >> 16)
                  : (u == 4) ? (u16)gR4.z : (u == 5) ? (u16)(gR4.z >> 16)
                  : (u == 6) ? (u16)gR4.w : (u16)(gR4.w >> 16);
          u16 gvz = (u == 0) ? (u16)gZ4.x : (u == 1) ? (u16)(gZ4.x >> 16)
                  : (u == 2) ? (u16)gZ4.y : (u == 3) ? (u16)(gZ4.y >> 16)
                  : (u == 4) ? (u16)gZ4.z : (u == 5) ? (u16)(gZ4.z >> 16)
                  : (u == 6) ? (u16)gZ4.w : (u16)(gZ4.w >> 16);
          u16 gvn = (u == 0) ? (u16)gN4.x : (u == 1) ? (u16)(gN4.x >> 16)
                  : (u == 2) ? (u16)gN4.y : (u == 3) ? (u16)(gN4.y >> 16)
                  : (u == 4) ? (u16)gN4.z : (u == 5) ? (u16)(gN4.z >> 16)
                  : (u == 6) ? (u16)gN4.w : (u16)(gN4.w >> 16);
          float pred = pred_s;
          gir = h2f(gvr) + pred * wr0;
          giz = h2f(gvz) + pred * wz0;
          gin = h2f(gvn) + pred * wn0;
        }
        float r = sigm(ar + gir);
        float z = sigm(az + giz);
        float n = tanh_fast(gin + r * (nd + bhn));
        hm = (1.f - z) * n + z * hm;
        Xp[cur ^ 1][j] = (f16)hm;
        if (is_enc) {
          u16 hv16 = f2h(hm);
          if (u == 0) hb0 = hv16; else if (u == 1) hb0 |= ((u32)hv16 << 16);
          else if (u == 2) hb1 = hv16; else if (u == 3) hb1 |= ((u32)hv16 << 16);
          else if (u == 4) hb2 = hv16; else if (u == 5) hb2 |= ((u32)hv16 << 16);
          else if (u == 6) hb3 = hv16; else hb3 |= ((u32)hv16 << 16);
        }
      }
      __syncthreads();                                 // B2: Xp(next) ready
      cur ^= 1;
    }
    if (is_enc && j < Hn) {
      uint4 o; o.x = hb0; o.y = hb1; o.z = hb2; o.w = hb3;
      *(uint4*)(hxrow + i8) = o;
    }
    if (!is_enc && j >= 192) ep = ec7;
  }
  // trailing couple for step Tc-1 + final batch store
  if (!is_enc && j >= 192) {
    float2 rr = couple(ep, Xp[cur]);
    if (lane3 == 0) {
      lp7 = rr.x; pr7 = rr.y; predreg = rr.y;
      *(float4*)(outlp + Tc - 8) = make_float4(lp0, lp1, lp2, lp3);
      *(float4*)(outlp + Tc - 4) = make_float4(lp4, lp5, lp6, lp7);
      *(float4*)(outpr + Tc - 8) = make_float4(pr0, pr1, pr2, pr3);
      *(float4*)(outpr + Tc - 4) = make_float4(pr4, pr5, pr6, pr7);
    }
  }
  if (j < Hn) (is_enc ? enc_h : dec_h)[(long)b * Hn + j] = hm;
  if (!is_enc && j == 192) dec_pred[b] = predreg;
}

// ---- GEMM: gi2[b][col][t] = hx[b][:][t]^T @ Wi_d[1:,:] + bi_d  (fp32 acc) ----
// A2 layout: [b][k][tt] ; C2 layout: [b][col][tt]  (both f16, t contiguous)
__global__ __launch_bounds__(256) void gemm_gi(
    const u16* __restrict__ A2, const float* __restrict__ Wi_d,
    const float* __restrict__ bi_d, u16* __restrict__ C2, int Tc)
{
  __shared__ __align__(16) float As[16][64];  // [k][m]
  __shared__ __align__(16) float Ws[16][64];  // [k][n]
  const int tid = threadIdx.x;
  const long m0 = (long)blockIdx.x * 64;      // m = b*Tc + tt
  const int n0 = blockIdx.y * 64;
  const int bb = (int)(m0 / Tc);
  const int tt0 = (int)(m0 - (long)bb * Tc);
  const int tx = tid & 15, ty = tid >> 4;
  const int lk = tid >> 4, lm = (tid & 15) * 4;   // A-load: k row, 4 tt's
  const int wk = tid >> 4, wn = (tid & 15) * 4;
  float acc[4][4] = {};
  for (int k0 = 0; k0 < Hn; k0 += 16) {
    uint2 a2v = *(const uint2*)(A2 + ((long)bb * Hn + k0 + lk) * Tc + tt0 + lm);
    float4 w4 = *(const float4*)(Wi_d + (long)(1 + k0 + wk) * G3 + n0 + wn);
    __syncthreads();
    As[lk][lm + 0] = h2f((u16)(a2v.x & 0xffffu));
    As[lk][lm + 1] = h2f((u16)(a2v.x >> 16));
    As[lk][lm + 2] = h2f((u16)(a2v.y & 0xffffu));
    As[lk][lm + 3] = h2f((u16)(a2v.y >> 16));
    *(float4*)&Ws[wk][wn] = w4;
    __syncthreads();
#pragma unroll
    for (int kk = 0; kk < 16; ++kk) {
      float4 av = *(const float4*)&As[kk][ty * 4];
      float4 wv = *(const float4*)&Ws[kk][tx * 4];
      float ar[4] = {av.x, av.y, av.z, av.w};
      float wr[4] = {wv.x, wv.y, wv.z, wv.w};
#pragma unroll
      for (int i = 0; i < 4; ++i)
#pragma unroll
        for (int jj = 0; jj < 4; ++jj) acc[i][jj] = fmaf(ar[i], wr[jj], acc[i][jj]);
    }
  }
  const float4 bbv = *(const float4*)(bi_d + n0 + tx * 4);
  const float br[4] = {bbv.x, bbv.y, bbv.z, bbv.w};
#pragma unroll
  for (int jj = 0; jj < 4; ++jj) {
    int colc = n0 + tx * 4 + jj;
    u32 lo = (u32)f2h(acc[0][jj] + br[jj]) | ((u32)f2h(acc[1][jj] + br[jj]) << 16);
    u32 hi = (u32)f2h(acc[2][jj] + br[jj]) | ((u32)f2h(acc[3][jj] + br[jj]) << 16);
    uint2 o; o.x = lo; o.y = hi;
    *(uint2*)(C2 + ((long)bb * G3 + colc) * Tc + tt0 + ty * 4) = o;
  }
}

extern "C" void kernel_launch(void* const* d_in, const int* in_sizes, int n_in,
                              void* d_out, int out_size, void* d_ws, size_t ws_size,
                              hipStream_t stream) {
  const float* x = (const float*)d_in[1];
  const float* eps = (const float*)d_in[2];
  const float* Wi_e = (const float*)d_in[3];
  const float* Wh_e = (const float*)d_in[4];
  const float* bi_e = (const float*)d_in[5];
  const float* bhn_e = (const float*)d_in[6];
  const float* Wi_d = (const float*)d_in[7];
  const float* Wh_d = (const float*)d_in[8];
  const float* bi_d = (const float*)d_in[9];
  const float* bhn_d = (const float*)d_in[10];
  const float* W_shift = (const float*)d_in[11];
  const float* b_shift = (const float*)d_in[12];
  const float* W_lsc = (const float*)d_in[13];
  const float* b_lsc = (const float*)d_in[14];
  const float* W_pi = (const float*)d_in[15];
  const float* b_pi = (const float*)d_in[16];
  const float* W_mu = (const float*)d_in[17];
  const float* b_mu = (const float*)d_in[18];
  const float* W_ls = (const float*)d_in[19];
  const float* b_ls = (const float*)d_in[20];
  float* out = (float*)d_out;

  const size_t stateB = (size_t)(2 * Bn * Hn + Bn) * sizeof(float);
  const size_t stateAl = (stateB + 255) & ~(size_t)255;
  int Tc = 512;  // 8 chunks: best measured config (R11)
  while (Tc > 64 && stateAl + (size_t)Bn * Tc * (Hn + G3) * 2 > ws_size) Tc >>= 1;
  if (stateAl + (size_t)Bn * Tc * (Hn + G3) * 2 > ws_size) return;

  float* enc_h = (float*)d_ws;
  float* dec_h = enc_h + (size_t)Bn * Hn;
  float* dec_pred = dec_h + (size_t)Bn * Hn;
  u16* hx = (u16*)((char*)d_ws + stateAl);          // [b][k][t]
  u16* gi = hx + (size_t)Bn * Tc * Hn;              // [b][col][t]

  const int Nc = Tn / Tc;
  const dim3 gg((unsigned)(((size_t)Bn * Tc) / 64), G3 / 64);
  for (int k = 0; k <= Nc; ++k) {
    int enc_t0 = (k < Nc) ? k * Tc : -1;
    int dec_t0 = (k >= 1) ? (k - 1) * Tc : -1;
    combo_kernel<<<2 * Bn, NTH, 0, stream>>>(
        x, Wi_e, Wh_e, bi_e, bhn_e, hx, enc_h,
        eps, Wi_d, Wh_d, bhn_d, W_shift, b_shift, W_lsc, b_lsc,
        W_pi, b_pi, W_mu, b_mu, W_ls, b_ls,
        gi, out, dec_h, dec_pred, enc_t0, dec_t0, Tc);
    if (k < Nc) gemm_gi<<<gg, 256, 0, stream>>>(hx, Wi_d, bi_d, gi, Tc);
  }
}